// Round 16
// baseline (141.560 us; speedup 1.0000x reference)
//
#include <hip/hip_runtime.h>

#define NB 16
#define NC 8
#define HW (512*512)
#define NT 16                 // tags 1..16 (tag 0 never participates)
#define LGG 3.0f

#define BLOCKS 1024           // 4 blocks/CU exactly (LDS-bound), all co-resident
#define THREADS 256
#define WPB 4
#define BPSAMP (BLOCKS/NB)    // 64 blocks per sample
#define PXB (HW/BPSAMP)       // 4096 pixels per block
#define TILE 512              // pixels per staged tile
#define NTILES (PXB/TILE)     // 8
#define JITERS 4              // 128 px per wave per j-iter
#define NCOL 10               // D cols: 0..7 ch sums, 8 count, 9 masked count
#define ACCW (NT*NCOL)        // 160 floats per slice

// double-buffered tile: [GK 2KB][MASK 2KB][SIM 8x2KB] = 20480 B per buffer
#define GK_OFF  0
#define MK_OFF  2048
#define SIM_OFF 4096
#define BUF_BYTES 20480
#define LDS_BYTES (2*BUF_BYTES)     // 40960 -> exactly 4 blocks/CU (do NOT exceed)

typedef __attribute__((ext_vector_type(8))) short bf16x8;
typedef __attribute__((ext_vector_type(4))) float f32x4;

__device__ __forceinline__ unsigned pk_bf16(float x, float y) {
    unsigned r;
    asm("v_cvt_pk_bf16_f32 %0, %1, %2" : "=v"(r) : "v"(x), "v"(y));
    return r;   // lo = bf16(x), hi = bf16(y), RNE
}
__device__ __forceinline__ unsigned onehot2(int a, int b, int r1) {
    return (a == r1 ? 0x3F80u : 0u) | (b == r1 ? 0x3F800000u : 0u);
}
__device__ __forceinline__ unsigned mask2(int a, int b) {
    return (a ? 0x3F80u : 0u) | (b ? 0x3F800000u : 0u);
}
__device__ __forceinline__ void gload_lds16(const void* g, void* lds) {
    __builtin_amdgcn_global_load_lds(
        (const __attribute__((address_space(1))) void*)g,
        (__attribute__((address_space(3))) void*)lds, 16, 0, 0);
}

// stage one 512-px tile: 20 x 1KB chunks, wave w takes idx = w, w+4, ... (5 each).
// sim plane p rotated by 16*p bytes within its 2KB (pre-swizzled GLOBAL src,
// linear LDS dest) to break the 2KB plane-stride bank conflict.
__device__ __forceinline__ void stage(const char* gkB, const char* mkB,
                                      const char* smB, char* buf,
                                      int t0b, int wid, int lane) {
    #pragma unroll
    for (int k = 0; k < 5; ++k) {
        const int idx = wid + 4 * k;
        const char* src; int dst;
        if (idx < 2) {
            src = gkB + t0b + idx * 1024 + lane * 16;
            dst = GK_OFF + idx * 1024 + lane * 16;
        } else if (idx < 4) {
            src = mkB + t0b + (idx - 2) * 1024 + lane * 16;
            dst = MK_OFF + (idx - 2) * 1024 + lane * 16;
        } else {
            const int s = idx - 4, p = s >> 1, h = s & 1;
            const int local = h * 1024 + lane * 16;
            const int goff = (local - 16 * p) & 2047;     // inverse rotation
            src = smB + (size_t)p * (HW * 4) + t0b + goff;
            dst = SIM_OFF + p * 2048 + local;
        }
        gload_lds16(src, buf + dst);
    }
}

// ws: psum[1024][160] f32 | sl[16] | sn[16] | scnt[16] u32 | gcnt u32
// scnt/gcnt zeroed by hipMemsetAsync each call; psum/sl/sn fully overwritten.
__global__ __launch_bounds__(THREADS) void accum(
    const int* __restrict__ gk, const int* __restrict__ mask,
    const float* __restrict__ sim, float* __restrict__ psum,
    float* __restrict__ sl, float* __restrict__ sn,
    unsigned* __restrict__ scnt, float* __restrict__ out)
{
    const int tid  = threadIdx.x;
    const int lane = tid & 63, wid = tid >> 6;
    const int bid  = blockIdx.x;
    const int b    = bid / BPSAMP;          // sample
    const int sb   = bid % BPSAMP;          // block within sample
    const int c    = lane & 15;             // D column role: 0..7 ch, 8 ones, 9 mask
    const int l4   = lane >> 4;             // k-chunk 0..3 (8 px each)
    const int base = sb * PXB;

    __shared__ __align__(16) char lds[LDS_BYTES];

    const char* gkB = (const char*)(gk   + (size_t)b * HW + base);
    const char* mkB = (const char*)(mask + (size_t)b * HW + base);
    const char* smB = (const char*)(sim  + (size_t)b * NC * HW + base);

    f32x4 acc = {0.f, 0.f, 0.f, 0.f};
    const int r1 = c + 1;
    const int pl = c & 7;                   // sim plane (c<8 lanes)
    const int rot = 16 * pl;

    stage(gkB, mkB, smB, lds, 0, wid, lane);            // tile 0 -> buf 0

    #pragma unroll 1
    for (int t = 0; t < NTILES; ++t) {
        char* cur = lds + (t & 1) * BUF_BYTES;
        if (t + 1 < NTILES) {
            stage(gkB, mkB, smB, lds + ((t + 1) & 1) * BUF_BYTES,
                  (t + 1) * (TILE * 4), wid, lane);
            asm volatile("s_waitcnt vmcnt(5)" ::: "memory");  // tile t drained;
        } else {                                              // t+1's 5 in flight
            asm volatile("s_waitcnt vmcnt(0)" ::: "memory");
        }
        __builtin_amdgcn_sched_barrier(0);
        __builtin_amdgcn_s_barrier();       // all waves' tile-t chunks visible

        #pragma unroll
        for (int j = 0; j < JITERS; ++j) {
            const int o = (wid * 128 + j * 32 + l4 * 8) * 4;  // byte off, <2048
            const int4 g0 = *(const int4*)(cur + GK_OFF + o);
            const int4 g1 = *(const int4*)(cur + GK_OFF + o + 16);
            float4 v0 = {0,0,0,0}, v1 = {0,0,0,0};
            if (c < 8) {
                const char* sp = cur + SIM_OFF + pl * 2048;
                v0 = *(const float4*)(sp + ((o + rot) & 2047));
                v1 = *(const float4*)(sp + ((o + 16 + rot) & 2047));
            }
            int4 m0 = {0,0,0,0}, m1 = {0,0,0,0};
            if (c == 9) {
                m0 = *(const int4*)(cur + MK_OFF + o);
                m1 = *(const int4*)(cur + MK_OFF + o + 16);
            }

            union { bf16x8 v; unsigned u[4]; } A, B;
            A.u[0] = onehot2(g0.x, g0.y, r1);
            A.u[1] = onehot2(g0.z, g0.w, r1);
            A.u[2] = onehot2(g1.x, g1.y, r1);
            A.u[3] = onehot2(g1.z, g1.w, r1);
            const unsigned bs0 = pk_bf16(v0.x, v0.y), bs1 = pk_bf16(v0.z, v0.w);
            const unsigned bs2 = pk_bf16(v1.x, v1.y), bs3 = pk_bf16(v1.z, v1.w);
            const unsigned bm0 = mask2(m0.x, m0.y), bm1 = mask2(m0.z, m0.w);
            const unsigned bm2 = mask2(m1.x, m1.y), bm3 = mask2(m1.z, m1.w);
            B.u[0] = c < 8 ? bs0 : (c == 8 ? 0x3F803F80u : (c == 9 ? bm0 : 0u));
            B.u[1] = c < 8 ? bs1 : (c == 8 ? 0x3F803F80u : (c == 9 ? bm1 : 0u));
            B.u[2] = c < 8 ? bs2 : (c == 8 ? 0x3F803F80u : (c == 9 ? bm2 : 0u));
            B.u[3] = c < 8 ? bs3 : (c == 8 ? 0x3F803F80u : (c == 9 ? bm3 : 0u));

            acc = __builtin_amdgcn_mfma_f32_16x16x32_bf16(A.v, B.v, acc, 0, 0, 0);
        }
        __builtin_amdgcn_s_barrier();       // reads done before parity overwrite
    }

    // ---- block reduce -> private psum slice ----
    float* F = (float*)lds;                 // overlay staging buffer (post-barrier)
    unsigned* U = (unsigned*)lds;           // flag slots at F[300..302]
    const int row0 = l4 * 4;                // D: col = lane&15, row = l4*4 + reg
    #pragma unroll
    for (int i = 0; i < 4; ++i) F[wid * 256 + (row0 + i) * 16 + c] = acc[i];
    __syncthreads();

    if (tid < ACCW) {                       // 160: r = tag row, cc = column
        const int r = tid / NCOL, cc = tid % NCOL;
        float s = 0.f;
        #pragma unroll
        for (int w = 0; w < WPB; ++w) s += F[w * 256 + r * 16 + cc];
        psum[(size_t)bid * ACCW + tid] = s;
    }
    __threadfence();                        // release psum stores (device scope)
    __syncthreads();
    if (tid == 0) {
        const unsigned old = atomicAdd(&scnt[b], 1u);
        U[300] = (old == BPSAMP - 1) ? 1u : 0u;
    }
    __syncthreads();

    // ---- per-sample finisher: last block of sample b ----
    if (U[300]) {
        __threadfence();                    // acquire: see all slices of sample b
        float s = 0.f;
        if (tid < ACCW) {
            const float* bp = psum + (size_t)b * BPSAMP * ACCW + tid;
            #pragma unroll 8
            for (int sI = 0; sI < BPSAMP; ++sI) s += bp[sI * ACCW];
        }
        __syncthreads();
        if (tid < ACCW) F[tid] = s;         // Sw[160]
        __syncthreads();
        if (tid < NT * NC) {                // means at F[160..287]
            const int t = tid >> 3, cc = tid & 7;
            F[160 + tid] = F[t * NCOL + cc] / fmaxf(F[t * NCOL + 8], 1.f);
        }
        if (wid == 0) {                     // presence bits (bit i = tag i+1)
            const unsigned bal =
                (unsigned)__ballot(lane < NT && F[lane * NCOL + 9] > 0.5f);
            if (lane == 0) U[301] = bal & 0xFFFFu;
        }
        __syncthreads();
        const unsigned pres = U[301];

        const int i = tid >> 4, j = tid & 15;    // exactly 256 pairs
        float loss = 0.f, nv = 0.f;
        if (i != j && ((pres >> i) & 1u) && ((pres >> j) & 1u)) {
            float d2 = 0.f;
            #pragma unroll
            for (int cc = 0; cc < NC; ++cc) {
                const float d = F[160 + i * 8 + cc] - F[160 + j * 8 + cc];
                d2 += d * d;
            }
            const float dist = sqrtf(d2 + 1e-12f);
            const float r = fmaxf(LGG - dist, 0.f);
            loss = logf(r * r + 1.f);
            nv = 1.f;
        }
        #pragma unroll
        for (int o = 32; o; o >>= 1) { loss += __shfl_xor(loss, o); nv += __shfl_xor(nv, o); }
        if (lane == 0) { F[288 + wid] = loss; F[292 + wid] = nv; }
        __syncthreads();
        if (tid == 0) {
            const float tl = F[288] + F[289] + F[290] + F[291];
            const float tn = F[292] + F[293] + F[294] + F[295];
            const float v = (__popc(pres) >= 2) ? 1.f : 0.f;
            sl[b] = v * (tl / fmaxf(tn, 1.f));
            sn[b] = v;
            __threadfence();                // release sl/sn
            const unsigned oldg = atomicAdd(&scnt[NB], 1u);   // global counter
            U[302] = (oldg == NB - 1) ? 1u : 0u;
        }
        __syncthreads();

        // ---- global finisher: last sample done combines 16 scalars ----
        if (U[302] && wid == 0) {
            __threadfence();                // acquire sl/sn
            float l = (lane < NB) ? sl[lane] : 0.f;
            float v = (lane < NB) ? sn[lane] : 0.f;
            #pragma unroll
            for (int o = 32; o; o >>= 1) { l += __shfl_xor(l, o); v += __shfl_xor(v, o); }
            if (lane == 0) out[0] = (v > 0.f) ? l / v : 0.f;
        }
    }
}

extern "C" void kernel_launch(void* const* d_in, const int* in_sizes, int n_in,
                              void* d_out, int out_size, void* d_ws, size_t ws_size,
                              hipStream_t stream) {
    const int*   gk   = (const int*)d_in[0];
    const int*   mask = (const int*)d_in[1];
    const float* sim  = (const float*)d_in[2];
    float* out  = (float*)d_out;

    float*    psum = (float*)d_ws;                       // 1024*160
    float*    sl   = psum + (size_t)BLOCKS * ACCW;       // 16
    float*    sn   = sl + NB;                            // 16
    unsigned* scnt = (unsigned*)(sn + NB);               // 16 per-sample + 1 global

    hipMemsetAsync(scnt, 0, (NB + 1) * sizeof(unsigned), stream);
    accum<<<BLOCKS, THREADS, 0, stream>>>(gk, mask, sim, psum, sl, sn, scnt, out);
}

// Round 17
// 45.027 us; speedup vs baseline: 3.1439x; 3.1439x over previous
//
#include <hip/hip_runtime.h>

#define NB 16
#define NC 8
#define HW (512*512)
#define NT 16                 // tags 1..16 (tag 0 never participates)
#define LGG 3.0f

#define BLOCKS 1024           // 4 blocks/CU exactly (LDS-bound), all co-resident
#define THREADS 256
#define WPB 4
#define BPSAMP (BLOCKS/NB)    // 64 blocks per sample
#define PXB (HW/BPSAMP)       // 4096 pixels per block
#define TILE 512              // pixels per staged tile
#define NTILES (PXB/TILE)     // 8
#define JITERS 4              // 128 px per wave per j-iter
#define NCOL 10               // D cols: 0..7 ch sums, 8 count, 9 masked count
#define ACCW (NT*NCOL)        // 160 floats per sample

// double-buffered tile: [GK 2KB][MASK 2KB][SIM 8x2KB] = 20480 B per buffer
#define GK_OFF  0
#define MK_OFF  2048
#define SIM_OFF 4096
#define BUF_BYTES 20480
#define LDS_BYTES (2*BUF_BYTES)     // 40960 -> exactly 4 blocks/CU

typedef __attribute__((ext_vector_type(8))) short bf16x8;
typedef __attribute__((ext_vector_type(4))) float f32x4;

__device__ __forceinline__ unsigned pk_bf16(float x, float y) {
    unsigned r;
    asm("v_cvt_pk_bf16_f32 %0, %1, %2" : "=v"(r) : "v"(x), "v"(y));
    return r;   // lo = bf16(x), hi = bf16(y), RNE
}
__device__ __forceinline__ unsigned onehot2(int a, int b, int r1) {
    return (a == r1 ? 0x3F80u : 0u) | (b == r1 ? 0x3F800000u : 0u);
}
__device__ __forceinline__ unsigned mask2(int a, int b) {
    return (a ? 0x3F80u : 0u) | (b ? 0x3F800000u : 0u);
}
__device__ __forceinline__ void gload_lds16(const void* g, void* lds) {
    __builtin_amdgcn_global_load_lds(
        (const __attribute__((address_space(1))) void*)g,
        (__attribute__((address_space(3))) void*)lds, 16, 0, 0);
}

// stage one 512-px tile: 20 x 1KB chunks, wave w takes idx = w, w+4, ... (5 each).
// sim plane p rotated by 16*p bytes within its 2KB (pre-swizzled GLOBAL src,
// linear LDS dest -- m173 pattern) to break the 2KB plane-stride bank conflict.
__device__ __forceinline__ void stage(const char* gkB, const char* mkB,
                                      const char* smB, char* buf,
                                      int t0b, int wid, int lane) {
    #pragma unroll
    for (int k = 0; k < 5; ++k) {
        const int idx = wid + 4 * k;
        const char* src; int dst;
        if (idx < 2) {
            src = gkB + t0b + idx * 1024 + lane * 16;
            dst = GK_OFF + idx * 1024 + lane * 16;
        } else if (idx < 4) {
            src = mkB + t0b + (idx - 2) * 1024 + lane * 16;
            dst = MK_OFF + (idx - 2) * 1024 + lane * 16;
        } else {
            const int s = idx - 4, p = s >> 1, h = s & 1;
            const int local = h * 1024 + lane * 16;
            const int goff = (local - 16 * p) & 2047;     // inverse rotation
            src = smB + (size_t)p * (HW * 4) + t0b + goff;
            dst = SIM_OFF + p * 2048 + local;
        }
        gload_lds16(src, buf + dst);
    }
}

__global__ __launch_bounds__(THREADS) void accum(
    const int* __restrict__ gk, const int* __restrict__ mask,
    const float* __restrict__ sim, float* __restrict__ g_acc)
{
    const int tid  = threadIdx.x;
    const int lane = tid & 63, wid = tid >> 6;
    const int bid  = blockIdx.x;
    const int b    = bid / BPSAMP;          // sample
    const int sb   = bid % BPSAMP;          // block within sample
    const int c    = lane & 15;             // D column role: 0..7 ch, 8 ones, 9 mask
    const int l4   = lane >> 4;             // k-chunk 0..3 (8 px each)
    const int base = sb * PXB;

    __shared__ __align__(16) char lds[LDS_BYTES];

    const char* gkB = (const char*)(gk   + (size_t)b * HW + base);
    const char* mkB = (const char*)(mask + (size_t)b * HW + base);
    const char* smB = (const char*)(sim  + (size_t)b * NC * HW + base);

    f32x4 acc = {0.f, 0.f, 0.f, 0.f};
    const int r1 = c + 1;
    const int pl = c & 7;                   // sim plane (c<8 lanes)
    const int rot = 16 * pl;

    stage(gkB, mkB, smB, lds, 0, wid, lane);            // tile 0 -> buf 0

    #pragma unroll 1
    for (int t = 0; t < NTILES; ++t) {
        char* cur = lds + (t & 1) * BUF_BYTES;
        if (t + 1 < NTILES) {
            stage(gkB, mkB, smB, lds + ((t + 1) & 1) * BUF_BYTES,
                  (t + 1) * (TILE * 4), wid, lane);
            asm volatile("s_waitcnt vmcnt(5)" ::: "memory");  // tile t drained;
        } else {                                              // t+1's 5 in flight
            asm volatile("s_waitcnt vmcnt(0)" ::: "memory");
        }
        __builtin_amdgcn_sched_barrier(0);
        __builtin_amdgcn_s_barrier();       // all waves' tile-t chunks visible

        #pragma unroll
        for (int j = 0; j < JITERS; ++j) {
            const int o = (wid * 128 + j * 32 + l4 * 8) * 4;  // byte off, <2048
            const int4 g0 = *(const int4*)(cur + GK_OFF + o);
            const int4 g1 = *(const int4*)(cur + GK_OFF + o + 16);
            float4 v0 = {0,0,0,0}, v1 = {0,0,0,0};
            if (c < 8) {
                const char* sp = cur + SIM_OFF + pl * 2048;
                v0 = *(const float4*)(sp + ((o + rot) & 2047));
                v1 = *(const float4*)(sp + ((o + 16 + rot) & 2047));
            }
            int4 m0 = {0,0,0,0}, m1 = {0,0,0,0};
            if (c == 9) {
                m0 = *(const int4*)(cur + MK_OFF + o);
                m1 = *(const int4*)(cur + MK_OFF + o + 16);
            }

            union { bf16x8 v; unsigned u[4]; } A, B;
            A.u[0] = onehot2(g0.x, g0.y, r1);
            A.u[1] = onehot2(g0.z, g0.w, r1);
            A.u[2] = onehot2(g1.x, g1.y, r1);
            A.u[3] = onehot2(g1.z, g1.w, r1);
            const unsigned bs0 = pk_bf16(v0.x, v0.y), bs1 = pk_bf16(v0.z, v0.w);
            const unsigned bs2 = pk_bf16(v1.x, v1.y), bs3 = pk_bf16(v1.z, v1.w);
            const unsigned bm0 = mask2(m0.x, m0.y), bm1 = mask2(m0.z, m0.w);
            const unsigned bm2 = mask2(m1.x, m1.y), bm3 = mask2(m1.z, m1.w);
            B.u[0] = c < 8 ? bs0 : (c == 8 ? 0x3F803F80u : (c == 9 ? bm0 : 0u));
            B.u[1] = c < 8 ? bs1 : (c == 8 ? 0x3F803F80u : (c == 9 ? bm1 : 0u));
            B.u[2] = c < 8 ? bs2 : (c == 8 ? 0x3F803F80u : (c == 9 ? bm2 : 0u));
            B.u[3] = c < 8 ? bs3 : (c == 8 ? 0x3F803F80u : (c == 9 ? bm3 : 0u));

            acc = __builtin_amdgcn_mfma_f32_16x16x32_bf16(A.v, B.v, acc, 0, 0, 0);
        }
        __builtin_amdgcn_s_barrier();       // reads done before parity overwrite
    }

    // ---- tail: block-reduce, then 160 atomicAdds into g_acc[b] (R12-proven) ----
    float* lred = (float*)lds;              // overlay buf0, post-barrier safe
    const int row0 = l4 * 4;                // D: col = lane&15, row = l4*4 + reg
    #pragma unroll
    for (int i = 0; i < 4; ++i) lred[wid * 256 + (row0 + i) * 16 + c] = acc[i];
    __syncthreads();

    if (tid < ACCW) {                       // 160: r = tag row, cc = column
        const int r = tid / NCOL, cc = tid % NCOL;
        float s = 0.f;
        #pragma unroll
        for (int w = 0; w < WPB; ++w) s += lred[w * 256 + r * 16 + cc];
        atomicAdd(&g_acc[b * ACCW + tid], s);
    }
}

__global__ __launch_bounds__(256) void finalize(
    const float* __restrict__ g_acc, float* __restrict__ out)
{
    __shared__ float    means[NB][NT][NC];
    __shared__ unsigned pres[NB];
    __shared__ float    sl[NB], sn[NB];
    const int tid = threadIdx.x;

    if (tid < NB) pres[tid] = 0u;
    __syncthreads();

    {
        const int b = tid >> 4, t = tid & 15;
        const float* row = g_acc + b * ACCW + t * NCOL;
        const float cnt = row[8];
        const float mc  = row[9];
        const float inv = 1.f / fmaxf(cnt, 1.f);
        #pragma unroll
        for (int cc = 0; cc < NC; ++cc) means[b][t][cc] = row[cc] * inv;
        if (mc > 0.5f) atomicOr(&pres[b], 1u << (t + 1));
    }
    __syncthreads();

    const int b = tid >> 4, i = tid & 15;          // sample, tag-1
    const unsigned pr = pres[b];                    // bits 1..16
    float loss = 0.f, nv = 0.f;
    if ((pr >> (i + 1)) & 1u) {
        #pragma unroll
        for (int j = 0; j < NT; ++j) {
            if (j != i && ((pr >> (j + 1)) & 1u)) {
                float d2 = 0.f;
                #pragma unroll
                for (int cc = 0; cc < NC; ++cc) {
                    const float d = means[b][i][cc] - means[b][j][cc];
                    d2 += d * d;
                }
                const float dist = sqrtf(d2 + 1e-12f);
                const float r = fmaxf(LGG - dist, 0.f);
                loss += logf(r * r + 1.f);
                nv += 1.f;
            }
        }
    }
    #pragma unroll
    for (int o = 8; o; o >>= 1) { loss += __shfl_xor(loss, o); nv += __shfl_xor(nv, o); }
    if (i == 0) {
        const float v = (__popc(pr) >= 2) ? 1.f : 0.f;
        sl[b] = v * (loss / fmaxf(nv, 1.f));
        sn[b] = v;
    }
    __syncthreads();
    if (tid == 0) {
        float tl = 0.f, tv = 0.f;
        for (int bb = 0; bb < NB; ++bb) { tl += sl[bb]; tv += sn[bb]; }
        out[0] = (tv > 0.f) ? tl / tv : 0.f;
    }
}

extern "C" void kernel_launch(void* const* d_in, const int* in_sizes, int n_in,
                              void* d_out, int out_size, void* d_ws, size_t ws_size,
                              hipStream_t stream) {
    const int*   gk   = (const int*)d_in[0];
    const int*   mask = (const int*)d_in[1];
    const float* sim  = (const float*)d_in[2];
    float* out   = (float*)d_out;
    float* g_acc = (float*)d_ws;      // NB*160 floats

    // zero the accumulators with a memset node (cheaper than a kernel launch)
    hipMemsetAsync(g_acc, 0, NB * ACCW * sizeof(float), stream);
    accum<<<BLOCKS, THREADS, 0, stream>>>(gk, mask, sim, g_acc);
    finalize<<<1, 256, 0, stream>>>(g_acc, out);
}